// Round 4
// baseline (668.755 us; speedup 1.0000x reference)
//
#include <hip/hip_runtime.h>

// DiffeqSolver: 49 RK4(3/8) steps of y' = W2 @ tanh(W1 @ y + b1) + b2
// 6144 rows, dim 128 (123+5 aug), hidden 256. Output (3,2048,50,128) fp32.
//
// Round 7: static priority staircase + compile-time group unroll.
//  - Round 6 measured MfmaUtil 50.5 + VALUBusy 51.4 (sum ~102%): the 4
//    waves/SIMD leave each barrier together, round-robin the matrix pipe,
//    finish MFMA bursts together, then serialize their VALU tails with the
//    matrix pipe idle. Interval = 1862(MFMA) + 1820(VALU) = 3554 cy.
//  - Fix: per-wave CONSTANT priority (3,2,1,0 per SIMD). Hi-prio waves drain
//    their MFMA burst first (~470 cy; chains stay issue-ready: A=6, B=3) and
//    run their VALU tail while lower-prio waves' MFMAs feed the pipe --
//    staggered completion instead of symmetric. pri = (w&3)^((w>>2)&3) gives
//    one wave of each level per SIMD under chunked OR round-robin mapping.
//    Old uniform setprio(1) toggles removed (they would mask the staircase).
//  - Interval loop unrolled x2: group index g is compile-time (no per-interval
//    base selects / branches; e = t2&3, s = t2>>2 shared by both groups).
//  - Structure otherwise round 6 (verified): 256x1024, 8 A-waves (W1, H=tanh)
//    + 8 B-waves (W2, K + RK fold + publish), 2 12-row groups skewed, frag-
//    linear conflict-free LDS, split precision x = hi(f16) + 2^-11 lo(f16).

typedef _Float16 half8  __attribute__((ext_vector_type(8)));
typedef _Float16 half4  __attribute__((ext_vector_type(4)));
typedef float    floatx4 __attribute__((ext_vector_type(4)));

#define NBLK 256
#define DIM  128
#define HID  256
#define ROWS 24           // rows per block (2 groups x 12)
#define GROWS 12
#define NT2  196          // unrolled interval pairs (= evals per group)
#define LOSCALE 2048.0f
#define LOINV   (1.0f/2048.0f)

__device__ __forceinline__ float fast_tanh(float x) {
    float e = __expf(2.0f * x);
    return 1.0f - 2.0f * __builtin_amdgcn_rcpf(e + 1.0f);
}

struct h2 { _Float16 hi, lo; };
__device__ __forceinline__ h2 split16(float v) {
    h2 r;
    r.hi = (_Float16)v;
    r.lo = (_Float16)((v - (float)r.hi) * LOSCALE);
    return r;
}

__global__ __launch_bounds__(1024, 4)
void ode_pri_kernel(const float* __restrict__ fp,      // (3,2048,123)
                    const float* __restrict__ tsteps,  // (50)
                    const float* __restrict__ W1,      // (256,128)
                    const float* __restrict__ b1,      // (256)
                    const float* __restrict__ W2,      // (128,256)
                    const float* __restrict__ b2,      // (128)
                    float* __restrict__ out)           // (3,2048,50,128)
{
    // frag-linear: element (batch n, k) at (k>>5)*512 + ((k>>3)&3)*128 + n*8 + (k&7)
    __shared__ __align__(16) _Float16 yfh[2][2048], yfl[2][2048];  // k=d  (128)
    __shared__ __align__(16) _Float16 hfh[2][4096], hfl[2][4096];  // k=h  (256)
    __shared__ float ts_l[64];

    const int tid  = threadIdx.x;
    const int wave = tid >> 6;
    const int lane = tid & 63;
    const int n16  = lane & 15;
    const int quad = lane >> 4;
    const int blk  = blockIdx.x;

    if (tid < 50) ts_l[tid] = tsteps[tid];

    // static priority staircase: one wave of each level 0..3 per SIMD under
    // both chunked (wave>>2) and round-robin (wave&3) wave->SIMD mappings.
    const int pri = (wave & 3) ^ ((wave >> 2) & 3);

    if (wave < 8) {
        // ============ producer A: H^T = tanh(W1 . Y^T + b1), 2 tiles =======
        const int a = wave;                    // h-rows [32a, 32a+32)
        half8 w1h[2][4], w1l[2][4];            // [i][kt]
        floatx4 bias1[2];
#pragma unroll
        for (int i = 0; i < 2; ++i) {
            bias1[i] = *(const floatx4*)(b1 + 32*a + 16*i + 4*quad);
#pragma unroll
            for (int kt = 0; kt < 4; ++kt) {
                const float* p = W1 + (32*a + 16*i + n16)*DIM + kt*32 + quad*8;
#pragma unroll
                for (int j = 0; j < 8; ++j) {
                    h2 sp = split16(p[j]);
                    w1h[i][kt][j] = sp.hi;
                    w1l[i][kt][j] = sp.lo;
                }
            }
        }
        const int yrd  = quad*128 + n16*8;               // + kt*512
        const int hwr  = a*512 + n16*8 + 4*(quad&1);     // + ((2i+hq)&3)*128
        const int hq   = quad >> 1;

        auto a_work = [&](int g) {
            floatx4 aM[2], aC[2], aD[2];
#pragma unroll
            for (int i = 0; i < 2; ++i) {
                aM[i] = bias1[i];
                aC[i] = (floatx4){0.f,0.f,0.f,0.f};
                aD[i] = (floatx4){0.f,0.f,0.f,0.f};
            }
#pragma unroll
            for (int kt = 0; kt < 4; ++kt) {
                half8 ybh = *(const half8*)&yfh[g][kt*512 + yrd];
                half8 ybl = *(const half8*)&yfl[g][kt*512 + yrd];
#pragma unroll
                for (int i = 0; i < 2; ++i) {
                    aM[i] = __builtin_amdgcn_mfma_f32_16x16x32_f16(w1h[i][kt], ybh, aM[i], 0,0,0);
                    aC[i] = __builtin_amdgcn_mfma_f32_16x16x32_f16(w1l[i][kt], ybh, aC[i], 0,0,0);
                    aD[i] = __builtin_amdgcn_mfma_f32_16x16x32_f16(w1h[i][kt], ybl, aD[i], 0,0,0);
                }
            }
#pragma unroll
            for (int i = 0; i < 2; ++i) {
                half4 th, tl;
#pragma unroll
                for (int r = 0; r < 4; ++r) {
                    const float v = aM[i][r] + LOINV*(aC[i][r] + aD[i][r]);
                    h2 sp = split16(fast_tanh(v));
                    th[r] = sp.hi; tl[r] = sp.lo;
                }
                const int off = hwr + ((2*i + hq) & 3)*128;
                *(half4*)&hfh[g][off] = th;
                *(half4*)&hfl[g][off] = tl;
            }
        };

        if      (pri == 3) __builtin_amdgcn_s_setprio(3);
        else if (pri == 2) __builtin_amdgcn_s_setprio(2);
        else if (pri == 1) __builtin_amdgcn_s_setprio(1);

        __syncthreads();                       // prologue: yf[0],yf[1] ready
#pragma unroll 1
        for (int t2 = 0; t2 < NT2; ++t2) {
            a_work(0);
            __syncthreads();
            a_work(1);
            __syncthreads();
        }
        __syncthreads();                       // matches B's final interval
    } else {
        // ====== consumer B: K^T = W2 . H^T + b2 ; RK fold ; publish yf =====
        const int wb = wave - 8;               // d-rows [16wb, 16wb+16)
        half8 w2h[8], w2l[8];                  // [kt]
        floatx4 bias2 = *(const floatx4*)(b2 + 16*wb + 4*quad);
#pragma unroll
        for (int kt = 0; kt < 8; ++kt) {
            const float* p = W2 + (16*wb + n16)*HID + kt*32 + quad*8;
#pragma unroll
            for (int j = 0; j < 8; ++j) {
                h2 sp = split16(p[j]);
                w2h[kt][j] = sp.hi;
                w2l[kt][j] = sp.lo;
            }
        }
        // per-lane state: d = 16wb + 4quad + r, row n16 (valid n16 < 12)
        const int d0 = 16*wb + 4*quad;
        floatx4 yg0 = (floatx4){0.f,0.f,0.f,0.f};
        floatx4 yg1 = (floatx4){0.f,0.f,0.f,0.f};
        floatx4 r10 = yg0, r11 = yg0, uu0 = yg0, uu1 = yg0;
        if (n16 < GROWS) {
#pragma unroll
            for (int r = 0; r < 4; ++r) {
                const int d = d0 + r;
                if (d < 123) {
                    yg0[r] = fp[(blk*ROWS + n16)*123 + d];
                    yg1[r] = fp[(blk*ROWS + GROWS + n16)*123 + d];
                }
            }
            // t = 0 output
            float* p0 = out + ((size_t)(blk*ROWS + n16)*50)*DIM + d0;
            float* p1 = out + ((size_t)(blk*ROWS + GROWS + n16)*50)*DIM + d0;
            *(floatx4*)p0 = yg0;
            *(floatx4*)p1 = yg1;
        }

        const int ywr = (wb>>1)*512 + ((2*wb + (quad>>1)) & 3)*128 + n16*8 + 4*(quad&1);
        auto publish = [&](int g, floatx4 p) {
            half4 hi, lo;
#pragma unroll
            for (int r = 0; r < 4; ++r) {
                h2 sp = split16(p[r]);
                hi[r] = sp.hi; lo[r] = sp.lo;
            }
            *(half4*)&yfh[g][ywr] = hi;
            *(half4*)&yfl[g][ywr] = lo;
        };
        publish(0, yg0);                       // e0 eval points = y0
        publish(1, yg1);

        const int hrd = quad*128 + n16*8;                // + kt*512

        auto b_work = [&](int g, floatx4 &yg, floatx4 &r1, floatx4 &uu,
                          int e, int s, float hstep) {
            floatx4 bM = bias2;
            floatx4 bC = (floatx4){0.f,0.f,0.f,0.f};
            floatx4 bD = (floatx4){0.f,0.f,0.f,0.f};
#pragma unroll
            for (int kt = 0; kt < 8; ++kt) {
                half8 hbh = *(const half8*)&hfh[g][kt*512 + hrd];
                half8 hbl = *(const half8*)&hfl[g][kt*512 + hrd];
                bM = __builtin_amdgcn_mfma_f32_16x16x32_f16(w2h[kt], hbh, bM, 0,0,0);
                bC = __builtin_amdgcn_mfma_f32_16x16x32_f16(w2l[kt], hbh, bC, 0,0,0);
                bD = __builtin_amdgcn_mfma_f32_16x16x32_f16(w2h[kt], hbl, bD, 0,0,0);
            }
            floatx4 kv;
#pragma unroll
            for (int r = 0; r < 4; ++r)
                kv[r] = bM[r] + LOINV*(bC[r] + bD[r]);

            floatx4 p;
            const float h3 = hstep * (1.0f/3.0f);
            if (e == 0) {            // k1: save, p2 = y + h/3 k1
                r1 = kv;
                p  = yg + h3*kv;
            } else if (e == 1) {     // k2: U=k1+3k2, D=k1-k2, p3 = y+h k2-h/3 k1
                uu = r1 + 3.0f*kv;
                p  = yg + hstep*kv - h3*r1;
                r1 = r1 - kv;
            } else if (e == 2) {     // k3: U+=3k3, p4 = y+h(D+k3)
                uu = uu + 3.0f*kv;
                p  = yg + hstep*(r1 + kv);
            } else {                 // k4: y += h/8 (U+k4); store
                yg = yg + hstep*0.125f*(uu + kv);
                p  = yg;
                if (n16 < GROWS) {
                    const int gr = blk*ROWS + g*GROWS + n16;
                    float* po = out + ((size_t)(gr*50 + s + 1))*DIM + d0;
                    *(floatx4*)po = p;
                }
            }
            publish(g, p);
        };

        if      (pri == 3) __builtin_amdgcn_s_setprio(3);
        else if (pri == 2) __builtin_amdgcn_s_setprio(2);
        else if (pri == 1) __builtin_amdgcn_s_setprio(1);

        __syncthreads();                       // prologue
        __syncthreads();                       // A's first work(0) interval
#pragma unroll 1
        for (int t2 = 0; t2 < NT2; ++t2) {
            const int e = t2 & 3;
            const int s = t2 >> 2;
            const float hstep = ts_l[s+1] - ts_l[s];
            b_work(0, yg0, r10, uu0, e, s, hstep);
            __syncthreads();
            b_work(1, yg1, r11, uu1, e, s, hstep);
            __syncthreads();
        }
    }
}

extern "C" void kernel_launch(void* const* d_in, const int* in_sizes, int n_in,
                              void* d_out, int out_size, void* d_ws, size_t ws_size,
                              hipStream_t stream) {
    const float* fp     = (const float*)d_in[0];
    const float* tsteps = (const float*)d_in[1];
    const float* W1     = (const float*)d_in[2];
    const float* b1     = (const float*)d_in[3];
    const float* W2     = (const float*)d_in[4];
    const float* b2     = (const float*)d_in[5];
    float* out          = (float*)d_out;

    ode_pri_kernel<<<NBLK, 1024, 0, stream>>>(fp, tsteps, W1, b1, W2, b2, out);
}

// Round 5
// 667.914 us; speedup vs baseline: 1.0013x; 1.0013x over previous
//
#include <hip/hip_runtime.h>

// DiffeqSolver: 49 RK4(3/8) steps of y' = W2 @ tanh(W1 @ y + b1) + b2
// 6144 rows, dim 128 (123+5 aug), hidden 256. Output (3,2048,50,128) fp32.
//
// Round 8: barrier-free directional flag sync (producer<->consumer).
//  - Rounds 6/7 measured MfmaUtil ~52 + VALUBusy ~51 = 103% of wall time:
//    zero pipe overlap, zero idle. The per-interval __syncthreads() re-locks
//    all 4 waves/SIMD into the same phase; MFMA bursts end together, VALU
//    tails run together with the matrix pipe idle. setprio staircase: null.
//  - Fix: remove the barrier. Two LDS epoch counters per group:
//      A epoch e:  wait cntB[g] >= 8e   -> read yf_e,  MFMA+tanh,
//                  write hf_e,  fence, cntA[g]++
//      B epoch e:  wait cntA[g] >= 8(e+1) -> read hf_e, MFMA, RK fold,
//                  publish yf_{e+1}, fence, cntB[g]++
//    yf/hf parity double-buffered (epoch&1) -> all WAR hazards covered by
//    the two gates (induction over epochs). A runs into epoch-e MFMA while
//    B is still in its epoch-(e-1) VALU tail: matrix pipe becomes binding
//    (~1862 cy/epoch-pair vs 3554 barrier-locked).
//  - Single 1024-thread block per CU (grid 256): all 16 waves co-resident by
//    construction -> LDS spin-wait is deadlock-safe. LDS 97 KB < 160.
//  - Everything else identical to round 7 (verified): 8 A-waves (W1 frags,
//    H = tanh), 8 B-waves (W2 frags, K + RK fold + publish), frag-linear
//    conflict-free LDS, split precision x = hi(f16) + 2^-11 lo(f16) with
//    3 MFMA products and unchanged summation order.

typedef _Float16 half8  __attribute__((ext_vector_type(8)));
typedef _Float16 half4  __attribute__((ext_vector_type(4)));
typedef float    floatx4 __attribute__((ext_vector_type(4)));

#define NBLK 256
#define DIM  128
#define HID  256
#define ROWS 24           // rows per block (2 groups x 12)
#define GROWS 12
#define NEV  196          // 49 steps x 4 evals, per group
#define LOSCALE 2048.0f
#define LOINV   (1.0f/2048.0f)

__device__ __forceinline__ float fast_tanh(float x) {
    float e = __expf(2.0f * x);
    return 1.0f - 2.0f * __builtin_amdgcn_rcpf(e + 1.0f);
}

struct h2 { _Float16 hi, lo; };
__device__ __forceinline__ h2 split16(float v) {
    h2 r;
    r.hi = (_Float16)v;
    r.lo = (_Float16)((v - (float)r.hi) * LOSCALE);
    return r;
}

__global__ __launch_bounds__(1024, 4)
void ode_flag_kernel(const float* __restrict__ fp,      // (3,2048,123)
                     const float* __restrict__ tsteps,  // (50)
                     const float* __restrict__ W1,      // (256,128)
                     const float* __restrict__ b1,      // (256)
                     const float* __restrict__ W2,      // (128,256)
                     const float* __restrict__ b2,      // (128)
                     float* __restrict__ out)           // (3,2048,50,128)
{
    // frag-linear: element (batch n, k) at (k>>5)*512 + ((k>>3)&3)*128 + n*8 + (k&7)
    // [group][parity][...]
    __shared__ __align__(16) _Float16 yfh[2][2][2048], yfl[2][2][2048];  // k=d (128)
    __shared__ __align__(16) _Float16 hfh[2][2][4096], hfl[2][2][4096];  // k=h (256)
    __shared__ float ts_l[64];
    __shared__ int cA[2], cB[2];   // epoch completion counters (x8 waves)

    const int tid  = threadIdx.x;
    const int wave = tid >> 6;
    const int lane = tid & 63;
    const int n16  = lane & 15;
    const int quad = lane >> 4;
    const int blk  = blockIdx.x;

    if (tid < 50) ts_l[tid] = tsteps[tid];
    if (tid < 2) { cA[tid] = 0; cB[tid] = 0; }

    if (wave < 8) {
        // ============ producer A: H^T = tanh(W1 . Y^T + b1), 2 tiles =======
        const int a = wave;                    // h-rows [32a, 32a+32)
        half8 w1h[2][4], w1l[2][4];            // [i][kt]
        floatx4 bias1[2];
#pragma unroll
        for (int i = 0; i < 2; ++i) {
            bias1[i] = *(const floatx4*)(b1 + 32*a + 16*i + 4*quad);
#pragma unroll
            for (int kt = 0; kt < 4; ++kt) {
                const float* p = W1 + (32*a + 16*i + n16)*DIM + kt*32 + quad*8;
#pragma unroll
                for (int j = 0; j < 8; ++j) {
                    h2 sp = split16(p[j]);
                    w1h[i][kt][j] = sp.hi;
                    w1l[i][kt][j] = sp.lo;
                }
            }
        }
        const int yrd  = quad*128 + n16*8;               // + kt*512
        const int hwr  = a*512 + n16*8 + 4*(quad&1);     // + ((2i+hq)&3)*128
        const int hq   = quad >> 1;

        auto a_work = [&](int g, int p) {
            floatx4 aM[2], aC[2], aD[2];
#pragma unroll
            for (int i = 0; i < 2; ++i) {
                aM[i] = bias1[i];
                aC[i] = (floatx4){0.f,0.f,0.f,0.f};
                aD[i] = (floatx4){0.f,0.f,0.f,0.f};
            }
#pragma unroll
            for (int kt = 0; kt < 4; ++kt) {
                half8 ybh = *(const half8*)&yfh[g][p][kt*512 + yrd];
                half8 ybl = *(const half8*)&yfl[g][p][kt*512 + yrd];
#pragma unroll
                for (int i = 0; i < 2; ++i) {
                    aM[i] = __builtin_amdgcn_mfma_f32_16x16x32_f16(w1h[i][kt], ybh, aM[i], 0,0,0);
                    aC[i] = __builtin_amdgcn_mfma_f32_16x16x32_f16(w1l[i][kt], ybh, aC[i], 0,0,0);
                    aD[i] = __builtin_amdgcn_mfma_f32_16x16x32_f16(w1h[i][kt], ybl, aD[i], 0,0,0);
                }
            }
#pragma unroll
            for (int i = 0; i < 2; ++i) {
                half4 th, tl;
#pragma unroll
                for (int r = 0; r < 4; ++r) {
                    const float v = aM[i][r] + LOINV*(aC[i][r] + aD[i][r]);
                    h2 sp = split16(fast_tanh(v));
                    th[r] = sp.hi; tl[r] = sp.lo;
                }
                const int off = hwr + ((2*i + hq) & 3)*128;
                *(half4*)&hfh[g][p][off] = th;
                *(half4*)&hfl[g][p][off] = tl;
            }
        };

        __syncthreads();                       // init: yf[*][0] + counters ready
#pragma unroll 2
        for (int e = 0; e < NEV; ++e) {
#pragma unroll
            for (int g = 0; g < 2; ++g) {
                if (e > 0) {                   // wait: yf_e published (8 B-waves)
                    volatile int* pf = &cB[g];
                    const int tgt = 8*e;
                    while (*pf < tgt) { }
                }
                __threadfence_block();         // acquire
                a_work(g, e & 1);
                __threadfence_block();         // release (writes before flag)
                if (lane == 0) atomicAdd(&cA[g], 1);
            }
        }
    } else {
        // ====== consumer B: K^T = W2 . H^T + b2 ; RK fold ; publish yf =====
        const int wb = wave - 8;               // d-rows [16wb, 16wb+16)
        half8 w2h[8], w2l[8];                  // [kt]
        floatx4 bias2 = *(const floatx4*)(b2 + 16*wb + 4*quad);
#pragma unroll
        for (int kt = 0; kt < 8; ++kt) {
            const float* p = W2 + (16*wb + n16)*HID + kt*32 + quad*8;
#pragma unroll
            for (int j = 0; j < 8; ++j) {
                h2 sp = split16(p[j]);
                w2h[kt][j] = sp.hi;
                w2l[kt][j] = sp.lo;
            }
        }
        // per-lane state: d = 16wb + 4quad + r, row n16 (valid n16 < 12)
        const int d0 = 16*wb + 4*quad;
        floatx4 yg0 = (floatx4){0.f,0.f,0.f,0.f};
        floatx4 yg1 = (floatx4){0.f,0.f,0.f,0.f};
        floatx4 r10 = yg0, r11 = yg0, uu0 = yg0, uu1 = yg0;
        if (n16 < GROWS) {
#pragma unroll
            for (int r = 0; r < 4; ++r) {
                const int d = d0 + r;
                if (d < 123) {
                    yg0[r] = fp[(blk*ROWS + n16)*123 + d];
                    yg1[r] = fp[(blk*ROWS + GROWS + n16)*123 + d];
                }
            }
            // t = 0 output
            float* p0 = out + ((size_t)(blk*ROWS + n16)*50)*DIM + d0;
            float* p1 = out + ((size_t)(blk*ROWS + GROWS + n16)*50)*DIM + d0;
            *(floatx4*)p0 = yg0;
            *(floatx4*)p1 = yg1;
        }

        const int ywr = (wb>>1)*512 + ((2*wb + (quad>>1)) & 3)*128 + n16*8 + 4*(quad&1);
        auto publish = [&](int g, int p, floatx4 v) {
            half4 hi, lo;
#pragma unroll
            for (int r = 0; r < 4; ++r) {
                h2 sp = split16(v[r]);
                hi[r] = sp.hi; lo[r] = sp.lo;
            }
            *(half4*)&yfh[g][p][ywr] = hi;
            *(half4*)&yfl[g][p][ywr] = lo;
        };
        publish(0, 0, yg0);                    // yf_0, parity 0
        publish(1, 0, yg1);

        const int hrd = quad*128 + n16*8;                // + kt*512

        auto b_work = [&](int g, int rp, int wp, floatx4 &yg, floatx4 &r1,
                          floatx4 &uu, int e, int s, float hstep) {
            floatx4 bM = bias2;
            floatx4 bC = (floatx4){0.f,0.f,0.f,0.f};
            floatx4 bD = (floatx4){0.f,0.f,0.f,0.f};
#pragma unroll
            for (int kt = 0; kt < 8; ++kt) {
                half8 hbh = *(const half8*)&hfh[g][rp][kt*512 + hrd];
                half8 hbl = *(const half8*)&hfl[g][rp][kt*512 + hrd];
                bM = __builtin_amdgcn_mfma_f32_16x16x32_f16(w2h[kt], hbh, bM, 0,0,0);
                bC = __builtin_amdgcn_mfma_f32_16x16x32_f16(w2l[kt], hbh, bC, 0,0,0);
                bD = __builtin_amdgcn_mfma_f32_16x16x32_f16(w2h[kt], hbl, bD, 0,0,0);
            }
            floatx4 kv;
#pragma unroll
            for (int r = 0; r < 4; ++r)
                kv[r] = bM[r] + LOINV*(bC[r] + bD[r]);

            floatx4 p;
            const float h3 = hstep * (1.0f/3.0f);
            if (e == 0) {            // k1: save, p2 = y + h/3 k1
                r1 = kv;
                p  = yg + h3*kv;
            } else if (e == 1) {     // k2: U=k1+3k2, D=k1-k2, p3 = y+h k2-h/3 k1
                uu = r1 + 3.0f*kv;
                p  = yg + hstep*kv - h3*r1;
                r1 = r1 - kv;
            } else if (e == 2) {     // k3: U+=3k3, p4 = y+h(D+k3)
                uu = uu + 3.0f*kv;
                p  = yg + hstep*(r1 + kv);
            } else {                 // k4: y += h/8 (U+k4); store
                yg = yg + hstep*0.125f*(uu + kv);
                p  = yg;
                if (n16 < GROWS) {
                    const int gr = blk*ROWS + g*GROWS + n16;
                    float* po = out + ((size_t)(gr*50 + s + 1))*DIM + d0;
                    *(floatx4*)po = p;
                }
            }
            publish(g, wp, p);
        };

        __syncthreads();                       // init: yf[*][0] + counters ready
#pragma unroll 2
        for (int e = 0; e < NEV; ++e) {
            const int erk = e & 3;
            const int s   = e >> 2;
            const float hstep = ts_l[s+1] - ts_l[s];
#pragma unroll
            for (int g = 0; g < 2; ++g) {
                {                              // wait: hf_e written (8 A-waves)
                    volatile int* pf = &cA[g];
                    const int tgt = 8*(e+1);
                    while (*pf < tgt) { }
                }
                __threadfence_block();         // acquire
                if (g == 0) b_work(0, e & 1, (e+1) & 1, yg0, r10, uu0, erk, s, hstep);
                else        b_work(1, e & 1, (e+1) & 1, yg1, r11, uu1, erk, s, hstep);
                __threadfence_block();         // release
                if (lane == 0) atomicAdd(&cB[g], 1);
            }
        }
    }
}

extern "C" void kernel_launch(void* const* d_in, const int* in_sizes, int n_in,
                              void* d_out, int out_size, void* d_ws, size_t ws_size,
                              hipStream_t stream) {
    const float* fp     = (const float*)d_in[0];
    const float* tsteps = (const float*)d_in[1];
    const float* W1     = (const float*)d_in[2];
    const float* b1     = (const float*)d_in[3];
    const float* W2     = (const float*)d_in[4];
    const float* b2     = (const float*)d_in[5];
    float* out          = (float*)d_out;

    ode_flag_kernel<<<NBLK, 1024, 0, stream>>>(fp, tsteps, W1, b1, W2, b2, out);
}

// Round 7
// 618.130 us; speedup vs baseline: 1.0819x; 1.0805x over previous
//
#include <hip/hip_runtime.h>

// DiffeqSolver: 49 RK4(3/8) steps of y' = W2 @ tanh(W1 @ y + b1) + b2
// 6144 rows, dim 128 (123+5 aug), hidden 256. Output (3,2048,50,128) fp32.
//
// Round 9b: VALU diet on the round-7 barrier structure (best: 578 us).
//  (9a failed compile: cvt_pkrtz returns __fp16x2, not _Float16x2 — fixed
//   with an __fp16-vector typedef + bit_cast; no logic change.)
//  - Empirical additive law (rounds 6-8): wall = MFMA-busy + VALU-busy
//    (1862 + 1813 = 3554 cy/interval); three sync topologies (barrier
//    lockstep, priority staircase, directional flag sync) all failed to
//    overlap the pipes. So: shrink the addends, not the schedule.
//  - cvt_pkrtz packed f32->f16 (1 inst / 2 elems, no insert/pack ops);
//    publishes are uint2 8B stores. hi is RTZ: residual <=2x larger,
//    split error 2^-22 -> 2^-21 (validated scheme has margin).
//  - kt=0 peeled: first MFMA of each chain takes bias/zero as the C
//    operand -> kills ~36 accumulator-init v_movs per work.
//  - B main loop: s-loop x 4 static-e bodies (no runtime e branch;
//    r1 = kv is a rename; hstep/h3/h8 hoisted per step).
//  - tanh = 1 - 2*rcp(exp2(K*x)+1), K = 2*log2(e): one mul + exp2.
//  - Structure unchanged: 256x1024, 8 A-waves (W1, H = tanh(W1 Y^T + b1)),
//    8 B-waves (W2, K = W2 H^T + b2, RK fold, publish), 2 12-row groups
//    skewed by one barrier interval, frag-linear conflict-free LDS,
//    split precision x = hi(f16) + 2^-11 lo(f16), 3 MFMA products.

typedef _Float16 half8  __attribute__((ext_vector_type(8)));
typedef __fp16   fp16x2 __attribute__((ext_vector_type(2)));   // cvt_pkrtz result
typedef float    floatx4 __attribute__((ext_vector_type(4)));
typedef unsigned int uint2v __attribute__((ext_vector_type(2)));

#define NBLK 256
#define DIM  128
#define HID  256
#define ROWS 24           // rows per block (2 groups x 12)
#define GROWS 12
#define LOSCALE 2048.0f
#define LOINV   (1.0f/2048.0f)
#define K_TANH  2.8853900817779268f   // 2*log2(e)

__device__ __forceinline__ float fast_tanh(float x) {
    float e = __builtin_amdgcn_exp2f(K_TANH * x);
    return 1.0f - 2.0f * __builtin_amdgcn_rcpf(e + 1.0f);
}

struct h2c { _Float16 hi, lo; };
__device__ __forceinline__ h2c split16(float v) {   // RTN; weights init only
    h2c r;
    r.hi = (_Float16)v;
    r.lo = (_Float16)((v - (float)r.hi) * LOSCALE);
    return r;
}

// packed split of 4 f32 -> (hi 4xf16, lo 4xf16) as uint2 each
__device__ __forceinline__ void split4_pk(floatx4 v, uint2v &hi, uint2v &lo) {
    fp16x2 h01 = __builtin_amdgcn_cvt_pkrtz(v[0], v[1]);
    fp16x2 h23 = __builtin_amdgcn_cvt_pkrtz(v[2], v[3]);
    float r0 = (v[0] - (float)h01[0]) * LOSCALE;
    float r1 = (v[1] - (float)h01[1]) * LOSCALE;
    float r2 = (v[2] - (float)h23[0]) * LOSCALE;
    float r3 = (v[3] - (float)h23[1]) * LOSCALE;
    fp16x2 l01 = __builtin_amdgcn_cvt_pkrtz(r0, r1);
    fp16x2 l23 = __builtin_amdgcn_cvt_pkrtz(r2, r3);
    hi[0] = __builtin_bit_cast(unsigned int, h01);
    hi[1] = __builtin_bit_cast(unsigned int, h23);
    lo[0] = __builtin_bit_cast(unsigned int, l01);
    lo[1] = __builtin_bit_cast(unsigned int, l23);
}

__global__ __launch_bounds__(1024, 4)
void ode_diet_kernel(const float* __restrict__ fp,      // (3,2048,123)
                     const float* __restrict__ tsteps,  // (50)
                     const float* __restrict__ W1,      // (256,128)
                     const float* __restrict__ b1,      // (256)
                     const float* __restrict__ W2,      // (128,256)
                     const float* __restrict__ b2,      // (128)
                     float* __restrict__ out)           // (3,2048,50,128)
{
    // frag-linear: element (batch n, k) at (k>>5)*512 + ((k>>3)&3)*128 + n*8 + (k&7)
    __shared__ __align__(16) _Float16 yfh[2][2048], yfl[2][2048];  // k=d  (128)
    __shared__ __align__(16) _Float16 hfh[2][4096], hfl[2][4096];  // k=h  (256)
    __shared__ float ts_l[64];

    const int tid  = threadIdx.x;
    const int wave = tid >> 6;
    const int lane = tid & 63;
    const int n16  = lane & 15;
    const int quad = lane >> 4;
    const int blk  = blockIdx.x;

    if (tid < 50) ts_l[tid] = tsteps[tid];

    const floatx4 Z = (floatx4){0.f, 0.f, 0.f, 0.f};

    if (wave < 8) {
        // ============ producer A: H^T = tanh(W1 . Y^T + b1), 2 tiles =======
        const int a = wave;                    // h-rows [32a, 32a+32)
        half8 w1h[2][4], w1l[2][4];            // [i][kt]
        floatx4 bias1[2];
#pragma unroll
        for (int i = 0; i < 2; ++i) {
            bias1[i] = *(const floatx4*)(b1 + 32*a + 16*i + 4*quad);
#pragma unroll
            for (int kt = 0; kt < 4; ++kt) {
                const float* p = W1 + (32*a + 16*i + n16)*DIM + kt*32 + quad*8;
#pragma unroll
                for (int j = 0; j < 8; ++j) {
                    h2c sp = split16(p[j]);
                    w1h[i][kt][j] = sp.hi;
                    w1l[i][kt][j] = sp.lo;
                }
            }
        }
        const int yrd  = quad*128 + n16*8;               // + kt*512
        const int hwr  = a*512 + n16*8 + 4*(quad&1);     // + ((2i+hq)&3)*128
        const int hq   = quad >> 1;

        auto a_work = [&](int g) {
            floatx4 aM[2], aC[2], aD[2];
            {   // kt = 0 peeled: bias / zero as C operand (no init movs)
                half8 ybh = *(const half8*)&yfh[g][yrd];
                half8 ybl = *(const half8*)&yfl[g][yrd];
#pragma unroll
                for (int i = 0; i < 2; ++i) {
                    aM[i] = __builtin_amdgcn_mfma_f32_16x16x32_f16(w1h[i][0], ybh, bias1[i], 0,0,0);
                    aC[i] = __builtin_amdgcn_mfma_f32_16x16x32_f16(w1l[i][0], ybh, Z, 0,0,0);
                    aD[i] = __builtin_amdgcn_mfma_f32_16x16x32_f16(w1h[i][0], ybl, Z, 0,0,0);
                }
            }
#pragma unroll
            for (int kt = 1; kt < 4; ++kt) {
                half8 ybh = *(const half8*)&yfh[g][kt*512 + yrd];
                half8 ybl = *(const half8*)&yfl[g][kt*512 + yrd];
#pragma unroll
                for (int i = 0; i < 2; ++i) {
                    aM[i] = __builtin_amdgcn_mfma_f32_16x16x32_f16(w1h[i][kt], ybh, aM[i], 0,0,0);
                    aC[i] = __builtin_amdgcn_mfma_f32_16x16x32_f16(w1l[i][kt], ybh, aC[i], 0,0,0);
                    aD[i] = __builtin_amdgcn_mfma_f32_16x16x32_f16(w1h[i][kt], ybl, aD[i], 0,0,0);
                }
            }
#pragma unroll
            for (int i = 0; i < 2; ++i) {
                floatx4 t;
#pragma unroll
                for (int r = 0; r < 4; ++r) {
                    const float v = aM[i][r] + LOINV*(aC[i][r] + aD[i][r]);
                    t[r] = fast_tanh(v);
                }
                uint2v hi, lo;
                split4_pk(t, hi, lo);
                const int off = hwr + ((2*i + hq) & 3)*128;
                *(uint2v*)&hfh[g][off] = hi;
                *(uint2v*)&hfl[g][off] = lo;
            }
        };

        __syncthreads();                       // prologue: yf[0],yf[1] ready
#pragma unroll 1
        for (int s = 0; s < 49; ++s) {
#pragma unroll 1
            for (int q = 0; q < 4; ++q) {
                a_work(0);
                __syncthreads();
                a_work(1);
                __syncthreads();
            }
        }
        __syncthreads();                       // matches B's trailing interval
    } else {
        // ====== consumer B: K^T = W2 . H^T + b2 ; RK fold ; publish yf =====
        const int wb = wave - 8;               // d-rows [16wb, 16wb+16)
        half8 w2h[8], w2l[8];                  // [kt]
        floatx4 bias2 = *(const floatx4*)(b2 + 16*wb + 4*quad);
#pragma unroll
        for (int kt = 0; kt < 8; ++kt) {
            const float* p = W2 + (16*wb + n16)*HID + kt*32 + quad*8;
#pragma unroll
            for (int j = 0; j < 8; ++j) {
                h2c sp = split16(p[j]);
                w2h[kt][j] = sp.hi;
                w2l[kt][j] = sp.lo;
            }
        }
        // per-lane state: d = 16wb + 4quad + r, row n16 (valid n16 < 12)
        const int d0 = 16*wb + 4*quad;
        floatx4 yg0 = Z, yg1 = Z, r10 = Z, r11 = Z, uu0 = Z, uu1 = Z;
        if (n16 < GROWS) {
#pragma unroll
            for (int r = 0; r < 4; ++r) {
                const int d = d0 + r;
                if (d < 123) {
                    yg0[r] = fp[(blk*ROWS + n16)*123 + d];
                    yg1[r] = fp[(blk*ROWS + GROWS + n16)*123 + d];
                }
            }
            // t = 0 output
            float* p0 = out + ((size_t)(blk*ROWS + n16)*50)*DIM + d0;
            float* p1 = out + ((size_t)(blk*ROWS + GROWS + n16)*50)*DIM + d0;
            *(floatx4*)p0 = yg0;
            *(floatx4*)p1 = yg1;
        }

        const int ywr = (wb>>1)*512 + ((2*wb + (quad>>1)) & 3)*128 + n16*8 + 4*(quad&1);
        auto publish = [&](int g, floatx4 p) {
            uint2v hi, lo;
            split4_pk(p, hi, lo);
            *(uint2v*)&yfh[g][ywr] = hi;
            *(uint2v*)&yfl[g][ywr] = lo;
        };
        publish(0, yg0);                       // e0 eval points = y0
        publish(1, yg1);

        const int hrd = quad*128 + n16*8;                // + kt*512
        auto b_mm = [&](int g) -> floatx4 {
            floatx4 bM, bC, bD;
            {   // kt = 0 peeled
                half8 hbh = *(const half8*)&hfh[g][hrd];
                half8 hbl = *(const half8*)&hfl[g][hrd];
                bM = __builtin_amdgcn_mfma_f32_16x16x32_f16(w2h[0], hbh, bias2, 0,0,0);
                bC = __builtin_amdgcn_mfma_f32_16x16x32_f16(w2l[0], hbh, Z, 0,0,0);
                bD = __builtin_amdgcn_mfma_f32_16x16x32_f16(w2h[0], hbl, Z, 0,0,0);
            }
#pragma unroll
            for (int kt = 1; kt < 8; ++kt) {
                half8 hbh = *(const half8*)&hfh[g][kt*512 + hrd];
                half8 hbl = *(const half8*)&hfl[g][kt*512 + hrd];
                bM = __builtin_amdgcn_mfma_f32_16x16x32_f16(w2h[kt], hbh, bM, 0,0,0);
                bC = __builtin_amdgcn_mfma_f32_16x16x32_f16(w2l[kt], hbh, bC, 0,0,0);
                bD = __builtin_amdgcn_mfma_f32_16x16x32_f16(w2h[kt], hbl, bD, 0,0,0);
            }
            floatx4 kv;
#pragma unroll
            for (int r = 0; r < 4; ++r)
                kv[r] = bM[r] + LOINV*(bC[r] + bD[r]);
            return kv;
        };

        __syncthreads();                       // prologue
        __syncthreads();                       // A's first a_work(0) interval
#pragma unroll 1
        for (int s = 0; s < 49; ++s) {
            const float hstep = ts_l[s+1] - ts_l[s];
            const float h3 = hstep * (1.0f/3.0f);
            const float h8 = hstep * 0.125f;
            // ---- e = 0: k1 -> r1; p2 = y + h/3 k1 ----
            { floatx4 k = b_mm(0); r10 = k; publish(0, yg0 + h3*k); }
            __syncthreads();
            { floatx4 k = b_mm(1); r11 = k; publish(1, yg1 + h3*k); }
            __syncthreads();
            // ---- e = 1: U = k1+3k2; p3 = y + h k2 - h/3 k1; r1 = k1-k2 ----
            { floatx4 k = b_mm(0); uu0 = r10 + 3.0f*k;
              publish(0, yg0 + hstep*k - h3*r10); r10 = r10 - k; }
            __syncthreads();
            { floatx4 k = b_mm(1); uu1 = r11 + 3.0f*k;
              publish(1, yg1 + hstep*k - h3*r11); r11 = r11 - k; }
            __syncthreads();
            // ---- e = 2: U += 3k3; p4 = y + h(D + k3) ----
            { floatx4 k = b_mm(0); uu0 = uu0 + 3.0f*k;
              publish(0, yg0 + hstep*(r10 + k)); }
            __syncthreads();
            { floatx4 k = b_mm(1); uu1 = uu1 + 3.0f*k;
              publish(1, yg1 + hstep*(r11 + k)); }
            __syncthreads();
            // ---- e = 3: y += h/8 (U + k4); store; p = y ----
            { floatx4 k = b_mm(0); yg0 = yg0 + h8*(uu0 + k);
              if (n16 < GROWS) {
                  const int gr = blk*ROWS + n16;
                  float* po = out + ((size_t)(gr*50 + s + 1))*DIM + d0;
                  *(floatx4*)po = yg0;
              }
              publish(0, yg0); }
            __syncthreads();
            { floatx4 k = b_mm(1); yg1 = yg1 + h8*(uu1 + k);
              if (n16 < GROWS) {
                  const int gr = blk*ROWS + GROWS + n16;
                  float* po = out + ((size_t)(gr*50 + s + 1))*DIM + d0;
                  *(floatx4*)po = yg1;
              }
              publish(1, yg1); }
            __syncthreads();
        }
    }
}

extern "C" void kernel_launch(void* const* d_in, const int* in_sizes, int n_in,
                              void* d_out, int out_size, void* d_ws, size_t ws_size,
                              hipStream_t stream) {
    const float* fp     = (const float*)d_in[0];
    const float* tsteps = (const float*)d_in[1];
    const float* W1     = (const float*)d_in[2];
    const float* b1     = (const float*)d_in[3];
    const float* W2     = (const float*)d_in[4];
    const float* b2     = (const float*)d_in[5];
    float* out          = (float*)d_out;

    ode_diet_kernel<<<NBLK, 1024, 0, stream>>>(fp, tsteps, W1, b1, W2, b2, out);
}

// Round 8
// 603.699 us; speedup vs baseline: 1.1078x; 1.0239x over previous
//
#include <hip/hip_runtime.h>

// DiffeqSolver: 49 RK4(3/8) steps of y' = W2 @ tanh(W1 @ y + b1) + b2
// 6144 rows, dim 128 (123+5 aug), hidden 256. Output (3,2048,50,128) fp32.
//
// Round 10: fat waves — halve LDS-read traffic (the REAL bottleneck).
//  - Corrected cycle model (fits rounds 4,6,7,9): wall = startup +
//    max(MFMA, LDS) + VALU-tail + barrier. At 16 waves the LDS pipe carried
//    192 ds_read_b128/interval/CU = ~2600 cy > MFMA 1862 cy -> LDS-bound at
//    ~3500 cy/interval. VALU was never binding (diet: -2%); sync topology
//    was never binding (3 nulls).
//  - Fix: operand reads scale with #waves consuming each LDS buffer. Go to
//    8 waves x 512 threads, launch_bounds(512,2) (256-VGPR cap): 4 A-waves
//    hold 4 h-tiles of W1 each (128 VGPR frags), 4 B-waves hold 2 d-tiles
//    of W2 (128 VGPR). Reads/interval: 4x8 + 4x16 = 96 (~1450 cy incl
//    writes) < MFMA 1862 cy -> matrix pipe becomes the binding resource.
//    Per-SIMD MFMA unchanged: 96 MFMA = 1862 cy/interval.
//  - Everything else from the verified r9b kernel: frag-linear conflict-free
//    LDS, 2 12-row groups skewed by one barrier interval, cvt_pkrtz packed
//    publishes, kt=0 peel, static-e RK bodies, exp2 tanh, split precision
//    x = hi(f16) + 2^-11 lo(f16) with 3 MFMA products.

typedef _Float16 half8  __attribute__((ext_vector_type(8)));
typedef __fp16   fp16x2 __attribute__((ext_vector_type(2)));   // cvt_pkrtz result
typedef float    floatx4 __attribute__((ext_vector_type(4)));
typedef unsigned int uint2v __attribute__((ext_vector_type(2)));

#define NBLK 256
#define DIM  128
#define HID  256
#define ROWS 24           // rows per block (2 groups x 12)
#define GROWS 12
#define LOSCALE 2048.0f
#define LOINV   (1.0f/2048.0f)
#define K_TANH  2.8853900817779268f   // 2*log2(e)

__device__ __forceinline__ float fast_tanh(float x) {
    float e = __builtin_amdgcn_exp2f(K_TANH * x);
    return 1.0f - 2.0f * __builtin_amdgcn_rcpf(e + 1.0f);
}

struct h2c { _Float16 hi, lo; };
__device__ __forceinline__ h2c split16(float v) {   // RTN; weights init only
    h2c r;
    r.hi = (_Float16)v;
    r.lo = (_Float16)((v - (float)r.hi) * LOSCALE);
    return r;
}

// packed split of 4 f32 -> (hi 4xf16, lo 4xf16) as uint2 each
__device__ __forceinline__ void split4_pk(floatx4 v, uint2v &hi, uint2v &lo) {
    fp16x2 h01 = __builtin_amdgcn_cvt_pkrtz(v[0], v[1]);
    fp16x2 h23 = __builtin_amdgcn_cvt_pkrtz(v[2], v[3]);
    float r0 = (v[0] - (float)h01[0]) * LOSCALE;
    float r1 = (v[1] - (float)h01[1]) * LOSCALE;
    float r2 = (v[2] - (float)h23[0]) * LOSCALE;
    float r3 = (v[3] - (float)h23[1]) * LOSCALE;
    fp16x2 l01 = __builtin_amdgcn_cvt_pkrtz(r0, r1);
    fp16x2 l23 = __builtin_amdgcn_cvt_pkrtz(r2, r3);
    hi[0] = __builtin_bit_cast(unsigned int, h01);
    hi[1] = __builtin_bit_cast(unsigned int, h23);
    lo[0] = __builtin_bit_cast(unsigned int, l01);
    lo[1] = __builtin_bit_cast(unsigned int, l23);
}

__global__ __launch_bounds__(512, 2)
void ode_fat_kernel(const float* __restrict__ fp,      // (3,2048,123)
                    const float* __restrict__ tsteps,  // (50)
                    const float* __restrict__ W1,      // (256,128)
                    const float* __restrict__ b1,      // (256)
                    const float* __restrict__ W2,      // (128,256)
                    const float* __restrict__ b2,      // (128)
                    float* __restrict__ out)           // (3,2048,50,128)
{
    // frag-linear: element (batch n, k) at (k>>5)*512 + ((k>>3)&3)*128 + n*8 + (k&7)
    __shared__ __align__(16) _Float16 yfh[2][2048], yfl[2][2048];  // k=d  (128)
    __shared__ __align__(16) _Float16 hfh[2][4096], hfl[2][4096];  // k=h  (256)
    __shared__ float ts_l[64];

    const int tid  = threadIdx.x;
    const int wave = tid >> 6;
    const int lane = tid & 63;
    const int n16  = lane & 15;
    const int quad = lane >> 4;
    const int hq   = quad >> 1;
    const int blk  = blockIdx.x;

    if (tid < 50) ts_l[tid] = tsteps[tid];

    const floatx4 Z = (floatx4){0.f, 0.f, 0.f, 0.f};

    if (wave < 4) {
        // ======= producer A: H^T = tanh(W1 . Y^T + b1), 4 tiles/wave =======
        const int a = wave;                    // h-rows [64a, 64a+64)
        half8 w1h[4][4], w1l[4][4];            // [i][kt]  (128 VGPR)
        floatx4 bias1[4];
#pragma unroll
        for (int i = 0; i < 4; ++i) {
            bias1[i] = *(const floatx4*)(b1 + 64*a + 16*i + 4*quad);
#pragma unroll
            for (int kt = 0; kt < 4; ++kt) {
                const float* p = W1 + (64*a + 16*i + n16)*DIM + kt*32 + quad*8;
#pragma unroll
                for (int j = 0; j < 8; ++j) {
                    h2c sp = split16(p[j]);
                    w1h[i][kt][j] = sp.hi;
                    w1l[i][kt][j] = sp.lo;
                }
            }
        }
        const int yrd = quad*128 + n16*8;                // + kt*512
        // publish offset for tile i: k = 64a + 16i + 4quad + r
        const int hwr = 2*a*512 + n16*8 + 4*(quad&1);    // + (i>>1)*512 + ((2i+hq)&3)*128

        auto a_work = [&](int g) {
            floatx4 aM[4], aC[4], aD[4];
            {   // kt = 0 peeled: bias / zero as C operand
                half8 ybh = *(const half8*)&yfh[g][yrd];
                half8 ybl = *(const half8*)&yfl[g][yrd];
#pragma unroll
                for (int i = 0; i < 4; ++i) {
                    aM[i] = __builtin_amdgcn_mfma_f32_16x16x32_f16(w1h[i][0], ybh, bias1[i], 0,0,0);
                    aC[i] = __builtin_amdgcn_mfma_f32_16x16x32_f16(w1l[i][0], ybh, Z, 0,0,0);
                    aD[i] = __builtin_amdgcn_mfma_f32_16x16x32_f16(w1h[i][0], ybl, Z, 0,0,0);
                }
            }
#pragma unroll
            for (int kt = 1; kt < 4; ++kt) {
                half8 ybh = *(const half8*)&yfh[g][kt*512 + yrd];
                half8 ybl = *(const half8*)&yfl[g][kt*512 + yrd];
#pragma unroll
                for (int i = 0; i < 4; ++i) {
                    aM[i] = __builtin_amdgcn_mfma_f32_16x16x32_f16(w1h[i][kt], ybh, aM[i], 0,0,0);
                    aC[i] = __builtin_amdgcn_mfma_f32_16x16x32_f16(w1l[i][kt], ybh, aC[i], 0,0,0);
                    aD[i] = __builtin_amdgcn_mfma_f32_16x16x32_f16(w1h[i][kt], ybl, aD[i], 0,0,0);
                }
            }
#pragma unroll
            for (int i = 0; i < 4; ++i) {
                floatx4 t;
#pragma unroll
                for (int r = 0; r < 4; ++r) {
                    const float v = aM[i][r] + LOINV*(aC[i][r] + aD[i][r]);
                    t[r] = fast_tanh(v);
                }
                uint2v hi, lo;
                split4_pk(t, hi, lo);
                const int off = hwr + (i>>1)*512 + ((2*i + hq) & 3)*128;
                *(uint2v*)&hfh[g][off] = hi;
                *(uint2v*)&hfl[g][off] = lo;
            }
        };

        __syncthreads();                       // prologue: yf[0],yf[1] ready
#pragma unroll 1
        for (int s = 0; s < 49; ++s) {
#pragma unroll 1
            for (int q = 0; q < 4; ++q) {
                a_work(0);
                __syncthreads();
                a_work(1);
                __syncthreads();
            }
        }
        __syncthreads();                       // matches B's trailing interval
    } else {
        // == consumer B: K^T = W2 . H^T + b2 ; RK fold ; publish, 2 tiles ===
        const int wb = wave - 4;               // d-rows [32wb, 32wb+32)
        half8 w2h[2][8], w2l[2][8];            // [j][kt]  (128 VGPR)
        floatx4 bias2[2];
#pragma unroll
        for (int j = 0; j < 2; ++j) {
            bias2[j] = *(const floatx4*)(b2 + 32*wb + 16*j + 4*quad);
#pragma unroll
            for (int kt = 0; kt < 8; ++kt) {
                const float* p = W2 + (32*wb + 16*j + n16)*HID + kt*32 + quad*8;
#pragma unroll
                for (int jj = 0; jj < 8; ++jj) {
                    h2c sp = split16(p[jj]);
                    w2h[j][kt][jj] = sp.hi;
                    w2l[j][kt][jj] = sp.lo;
                }
            }
        }
        // per-lane state: tile j holds d = 32wb + 16j + 4quad + r, row n16
        floatx4 yg0[2] = {Z, Z}, yg1[2] = {Z, Z};
        floatx4 r10[2] = {Z, Z}, r11[2] = {Z, Z};
        floatx4 uu0[2] = {Z, Z}, uu1[2] = {Z, Z};
        if (n16 < GROWS) {
#pragma unroll
            for (int j = 0; j < 2; ++j) {
                const int dj = 32*wb + 16*j + 4*quad;
#pragma unroll
                for (int r = 0; r < 4; ++r) {
                    const int d = dj + r;
                    if (d < 123) {
                        yg0[j][r] = fp[(blk*ROWS + n16)*123 + d];
                        yg1[j][r] = fp[(blk*ROWS + GROWS + n16)*123 + d];
                    }
                }
            }
            // t = 0 output
            float* p0 = out + ((size_t)(blk*ROWS + n16)*50)*DIM + 32*wb + 4*quad;
            float* p1 = out + ((size_t)(blk*ROWS + GROWS + n16)*50)*DIM + 32*wb + 4*quad;
            *(floatx4*)&p0[0]  = yg0[0];
            *(floatx4*)&p0[16] = yg0[1];
            *(floatx4*)&p1[0]  = yg1[0];
            *(floatx4*)&p1[16] = yg1[1];
        }

        // publish offset, tile j: k = 32wb + 16j + 4quad + r
        const int ywr = wb*512 + n16*8 + 4*(quad&1);     // + ((2j+hq)&3)*128
        auto publish = [&](int g, const floatx4* p) {
#pragma unroll
            for (int j = 0; j < 2; ++j) {
                uint2v hi, lo;
                split4_pk(p[j], hi, lo);
                const int off = ywr + ((2*j + hq) & 3)*128;
                *(uint2v*)&yfh[g][off] = hi;
                *(uint2v*)&yfl[g][off] = lo;
            }
        };
        publish(0, yg0);                       // e0 eval points = y0
        publish(1, yg1);

        const int hrd = quad*128 + n16*8;                // + kt*512
        auto b_mm = [&](int g, floatx4* kv) {
            floatx4 bM[2], bC[2], bD[2];
            {   // kt = 0 peeled
                half8 hbh = *(const half8*)&hfh[g][hrd];
                half8 hbl = *(const half8*)&hfl[g][hrd];
#pragma unroll
                for (int j = 0; j < 2; ++j) {
                    bM[j] = __builtin_amdgcn_mfma_f32_16x16x32_f16(w2h[j][0], hbh, bias2[j], 0,0,0);
                    bC[j] = __builtin_amdgcn_mfma_f32_16x16x32_f16(w2l[j][0], hbh, Z, 0,0,0);
                    bD[j] = __builtin_amdgcn_mfma_f32_16x16x32_f16(w2h[j][0], hbl, Z, 0,0,0);
                }
            }
#pragma unroll
            for (int kt = 1; kt < 8; ++kt) {
                half8 hbh = *(const half8*)&hfh[g][kt*512 + hrd];
                half8 hbl = *(const half8*)&hfl[g][kt*512 + hrd];
#pragma unroll
                for (int j = 0; j < 2; ++j) {
                    bM[j] = __builtin_amdgcn_mfma_f32_16x16x32_f16(w2h[j][kt], hbh, bM[j], 0,0,0);
                    bC[j] = __builtin_amdgcn_mfma_f32_16x16x32_f16(w2l[j][kt], hbh, bC[j], 0,0,0);
                    bD[j] = __builtin_amdgcn_mfma_f32_16x16x32_f16(w2h[j][kt], hbl, bD[j], 0,0,0);
                }
            }
#pragma unroll
            for (int j = 0; j < 2; ++j)
#pragma unroll
                for (int r = 0; r < 4; ++r)
                    kv[j][r] = bM[j][r] + LOINV*(bC[j][r] + bD[j][r]);
        };

        __syncthreads();                       // prologue
        __syncthreads();                       // A's first a_work(0) interval
#pragma unroll 1
        for (int s = 0; s < 49; ++s) {
            const float hstep = ts_l[s+1] - ts_l[s];
            const float h3 = hstep * (1.0f/3.0f);
            const float h8 = hstep * 0.125f;
            floatx4 k[2], pb[2];
            // ---- e = 0: k1 -> r1; p2 = y + h/3 k1 ----
            b_mm(0, k);
#pragma unroll
            for (int j = 0; j < 2; ++j) { r10[j] = k[j]; pb[j] = yg0[j] + h3*k[j]; }
            publish(0, pb);
            __syncthreads();
            b_mm(1, k);
#pragma unroll
            for (int j = 0; j < 2; ++j) { r11[j] = k[j]; pb[j] = yg1[j] + h3*k[j]; }
            publish(1, pb);
            __syncthreads();
            // ---- e = 1: U = k1+3k2; p3 = y + h k2 - h/3 k1; r1 = k1-k2 ----
            b_mm(0, k);
#pragma unroll
            for (int j = 0; j < 2; ++j) {
                uu0[j] = r10[j] + 3.0f*k[j];
                pb[j]  = yg0[j] + hstep*k[j] - h3*r10[j];
                r10[j] = r10[j] - k[j];
            }
            publish(0, pb);
            __syncthreads();
            b_mm(1, k);
#pragma unroll
            for (int j = 0; j < 2; ++j) {
                uu1[j] = r11[j] + 3.0f*k[j];
                pb[j]  = yg1[j] + hstep*k[j] - h3*r11[j];
                r11[j] = r11[j] - k[j];
            }
            publish(1, pb);
            __syncthreads();
            // ---- e = 2: U += 3k3; p4 = y + h(D + k3) ----
            b_mm(0, k);
#pragma unroll
            for (int j = 0; j < 2; ++j) {
                uu0[j] = uu0[j] + 3.0f*k[j];
                pb[j]  = yg0[j] + hstep*(r10[j] + k[j]);
            }
            publish(0, pb);
            __syncthreads();
            b_mm(1, k);
#pragma unroll
            for (int j = 0; j < 2; ++j) {
                uu1[j] = uu1[j] + 3.0f*k[j];
                pb[j]  = yg1[j] + hstep*(r11[j] + k[j]);
            }
            publish(1, pb);
            __syncthreads();
            // ---- e = 3: y += h/8 (U + k4); store; p = y ----
            b_mm(0, k);
#pragma unroll
            for (int j = 0; j < 2; ++j) yg0[j] = yg0[j] + h8*(uu0[j] + k[j]);
            if (n16 < GROWS) {
                float* po = out + ((size_t)((blk*ROWS + n16)*50 + s + 1))*DIM + 32*wb + 4*quad;
                *(floatx4*)&po[0]  = yg0[0];
                *(floatx4*)&po[16] = yg0[1];
            }
            publish(0, yg0);
            __syncthreads();
            b_mm(1, k);
#pragma unroll
            for (int j = 0; j < 2; ++j) yg1[j] = yg1[j] + h8*(uu1[j] + k[j]);
            if (n16 < GROWS) {
                float* po = out + ((size_t)((blk*ROWS + GROWS + n16)*50 + s + 1))*DIM + 32*wb + 4*quad;
                *(floatx4*)&po[0]  = yg1[0];
                *(floatx4*)&po[16] = yg1[1];
            }
            publish(1, yg1);
            __syncthreads();
        }
    }
}

extern "C" void kernel_launch(void* const* d_in, const int* in_sizes, int n_in,
                              void* d_out, int out_size, void* d_ws, size_t ws_size,
                              hipStream_t stream) {
    const float* fp     = (const float*)d_in[0];
    const float* tsteps = (const float*)d_in[1];
    const float* W1     = (const float*)d_in[2];
    const float* b1     = (const float*)d_in[3];
    const float* W2     = (const float*)d_in[4];
    const float* b2     = (const float*)d_in[5];
    float* out          = (float*)d_out;

    ode_fat_kernel<<<NBLK, 512, 0, stream>>>(fp, tsteps, W1, b1, W2, b2, out);
}